// Round 8
// baseline (5954.298 us; speedup 1.0000x reference)
//
#include <hip/hip_runtime.h>
#include <hip/hip_fp16.h>
#include <stdint.h>

#define S_LEN 1024
#define BATCH 64
#define HID   512
#define VOC   256

typedef _Float16 h2v __attribute__((ext_vector_type(2)));
typedef _Float16 h8v __attribute__((ext_vector_type(8)));
typedef float    f4v __attribute__((ext_vector_type(4)));

__device__ __forceinline__ float fdot2f(uint32_t w, uint32_t h, float c) {
#if __has_builtin(__builtin_amdgcn_fdot2)
  return __builtin_amdgcn_fdot2(__builtin_bit_cast(h2v, w),
                                __builtin_bit_cast(h2v, h), c, false);
#else
  h2v a = __builtin_bit_cast(h2v, w);
  h2v b = __builtin_bit_cast(h2v, h);
  return c + (float)a.x * (float)b.x + (float)a.y * (float)b.y;
#endif
}

// ---------------- prep kernels ----------------
// Wp[k2*HID + n] = fp16 pair (W_hh[2*k2][n], W_hh[2*k2+1][n]); also zeroes flags
__global__ void prep_whh(const float* __restrict__ whh, uint32_t* __restrict__ wp,
                         uint32_t* __restrict__ flags) {
  int idx = blockIdx.x * blockDim.x + threadIdx.x;   // 131072
  if (idx < 256) flags[idx] = 0u;                    // reset epochs EVERY launch
  int k2 = idx >> 9;
  int n  = idx & 511;
  float a = whh[(2 * k2) * HID + n];
  float b = whh[(2 * k2 + 1) * HID + n];
  h2v p;
  p.x = (_Float16)a;
  p.y = (_Float16)b;
  wp[idx] = __builtin_bit_cast(uint32_t, p);
}

// W_hyT[v*HID + k] = fp16 W_hy[k][v]
__global__ void prep_why(const float* __restrict__ why, _Float16* __restrict__ wt) {
  int idx = blockIdx.x * blockDim.x + threadIdx.x;   // 131072
  int v = idx >> 9;
  int k = idx & 511;
  wt[idx] = (_Float16)why[k * VOC + v];
}

// ---------------- phase 1: recurrence, split-K over 4 CUs per chain ------------
// grid 256: bid = p*64 + c (part p in [0,4), chain c in [0,64)).
// bid%8 == c%8  ->  all 4 parts of a chain share one XCD's L2.
// Each part owns k in [128p, 128p+128): 32 packed-pair VGPRs per thread.
// Per step: partial GEMV -> parity-double-buffered L2 partials; epoch flag
// (release); tid<4 spin on sibling flags (>= t+1, monotone within launch;
// flags zeroed by prep each launch); barrier; redundant reduce+tanh -> local h.
__global__ __launch_bounds__(1024, 4) void rnn_phase1(
    const int* __restrict__ x, const float* __restrict__ wih,
    const uint32_t* __restrict__ wp, const float* __restrict__ bh,
    __half* __restrict__ hbuf, float* __restrict__ pbuf /* [2][64][4][512] */,
    uint32_t* __restrict__ flags /* [64][4] */) {
  __shared__ __align__(16) uint32_t h2s[HID / 2];  // full h as fp16 pairs (1 KB)
  __shared__ int xtok[S_LEN];                      // 4 KB token row

  const int bid = blockIdx.x;
  const int p   = bid >> 6;          // part
  const int c   = bid & 63;          // chain
  const int tid = threadIdx.x;
  const int n   = tid >> 1;          // output column 0..511 (2 threads/col)
  const int j   = tid & 1;           // k2 half-slice
  const int k2b = p * 64 + j * 32;   // this thread's 32 k2-pairs

  // weights: 32 packed fp16 pairs = 32 VGPRs (low pressure, stays resident)
  uint32_t w[32];
#pragma unroll
  for (int i = 0; i < 32; ++i) w[i] = wp[(k2b + i) * HID + n];

  xtok[tid] = x[c * S_LEN + tid];
  if (tid < HID / 2) h2s[tid] = 0u;  // h0 = 0
  const float bh_r = (tid < HID) ? bh[tid] : 0.f;
  __syncthreads();

  uint32_t* myflag = &flags[c * 4 + p];

  for (int t = 0; t < S_LEN; ++t) {
    const int tok = xtok[t];
    float xe = 0.f;
    if (tid < HID) xe = wih[tok * HID + tid];  // early issue; used in reduce

    // partial dot over own 32 k2-pairs (h2s broadcast reads, conflict-free)
    float acc = 0.f;
    const uint4* hq = (const uint4*)&h2s[k2b];
#pragma unroll
    for (int q = 0; q < 8; ++q) {
      const uint4 hc = hq[q];
      acc = fdot2f(w[q * 4 + 0], hc.x, acc);
      acc = fdot2f(w[q * 4 + 1], hc.y, acc);
      acc = fdot2f(w[q * 4 + 2], hc.z, acc);
      acc = fdot2f(w[q * 4 + 3], hc.w, acc);
    }
    acc += __shfl_xor(acc, 1);  // combine the two k2-halves of this column

    // publish partial (agent-scope store -> L2, parity double-buffer)
    if (j == 0)
      __hip_atomic_store(&pbuf[(((t & 1) * 64 + c) * 4 + p) * 512 + n], acc,
                         __ATOMIC_RELAXED, __HIP_MEMORY_SCOPE_AGENT);

    __syncthreads();  // B1: all h2s reads of step t done; partial stores issued

    if (tid == 0)
      __hip_atomic_store(myflag, (uint32_t)(t + 1), __ATOMIC_RELEASE,
                         __HIP_MEMORY_SCOPE_AGENT);

    // tid<4 (one per sibling) spin; >= is skew-safe (monotone within launch)
    if (tid < 4 && tid != p) {
      while (__hip_atomic_load(&flags[c * 4 + tid], __ATOMIC_ACQUIRE,
                               __HIP_MEMORY_SCOPE_AGENT) < (uint32_t)(t + 1)) {}
    }
    __syncthreads();  // B-spin: whole block waits for the 3 pollers

    if (tid < HID) {
      const float* pb = &pbuf[(((t & 1) * 64 + c) * 4) * 512 + tid];
      float s = 0.f;
#pragma unroll
      for (int pp = 0; pp < 4; ++pp)
        s += __hip_atomic_load(pb + pp * 512, __ATOMIC_RELAXED,
                               __HIP_MEMORY_SCOPE_AGENT);  // L2 access, no stale L1
      s += xe + bh_r;
      const float e = __builtin_amdgcn_exp2f(s * 2.885390081777927f);  // e^(2s)
      const float h = 1.0f - 2.0f * __builtin_amdgcn_rcpf(e + 1.0f);
      const __half hh = __float2half(h);
      if (p == 0) hbuf[(size_t)(t * BATCH + c) * HID + tid] = hh;  // history
      ((__half*)h2s)[tid] = hh;  // rebuild full h locally
    }
    __syncthreads();  // B2: new h visible for step t+1
  }
}

// ---------------- phase 2: y = h @ W_hy + b_y (fp16 MFMA, in-place over d_out) ----
__global__ __launch_bounds__(256, 1) void rnn_phase2(
    void* __restrict__ out_, const _Float16* __restrict__ wt,
    const float* __restrict__ by) {
  const int tid = threadIdx.x;
  const int w = tid >> 6;
  const int l = tid & 63;
  const int la = l & 15;
  const int lb = l >> 4;
  const int rowbase = blockIdx.x * 64 + w * 16;

  const _Float16* hb = (const _Float16*)out_;
  float* out = (float*)out_;

  h8v a[16];
  const _Float16* arow = hb + (size_t)(rowbase + la) * HID + lb * 8;
#pragma unroll
  for (int kk = 0; kk < 16; ++kk)
    a[kk] = *((const h8v*)(arow + kk * 32));

#pragma unroll 1
  for (int cb = 0; cb < 16; ++cb) {
    f4v acc = {0.f, 0.f, 0.f, 0.f};
    const _Float16* brow = wt + (size_t)(cb * 16 + la) * HID + lb * 8;
#pragma unroll
    for (int kk = 0; kk < 16; ++kk) {
      const h8v bf = *((const h8v*)(brow + kk * 32));
      acc = __builtin_amdgcn_mfma_f32_16x16x32_f16(a[kk], bf, acc, 0, 0, 0);
    }
    const int col = cb * 16 + la;
    const float byv = by[col];
#pragma unroll
    for (int r = 0; r < 4; ++r) {
      const int row = rowbase + lb * 4 + r;
      out[(size_t)row * VOC + col] = acc[r] + byv;
    }
  }
}

// ---------------- launch ----------------
extern "C" void kernel_launch(void* const* d_in, const int* in_sizes, int n_in,
                              void* d_out, int out_size, void* d_ws, size_t ws_size,
                              hipStream_t stream) {
  const int*   x   = (const int*)d_in[0];
  const float* wih = (const float*)d_in[1];
  const float* whh = (const float*)d_in[2];
  const float* bh  = (const float*)d_in[3];
  const float* why = (const float*)d_in[4];
  const float* by  = (const float*)d_in[5];

  uint32_t* wp    = (uint32_t*)d_ws;                              // 512 KB packed W_hh
  _Float16* wt    = (_Float16*)((char*)d_ws + 512 * 1024);        // 256 KB W_hy^T
  float*    pbuf  = (float*)((char*)d_ws + 768 * 1024);           // 1 MB partials [2][64][4][512]
  uint32_t* flags = (uint32_t*)((char*)d_ws + 768 * 1024 + 1024 * 1024);  // 1 KB epochs

  hipLaunchKernelGGL(prep_whh, dim3(512), dim3(256), 0, stream, whh, wp, flags);
  hipLaunchKernelGGL(prep_why, dim3(512), dim3(256), 0, stream, why, wt);
  hipLaunchKernelGGL(rnn_phase1, dim3(256), dim3(1024), 0, stream,
                     x, wih, wp, bh, (__half*)d_out, pbuf, flags);
  hipLaunchKernelGGL(rnn_phase2, dim3((S_LEN * BATCH) / 64), dim3(256), 0, stream,
                     d_out, wt, by);
}

// Round 9
// 1627.258 us; speedup vs baseline: 3.6591x; 3.6591x over previous
//
#include <hip/hip_runtime.h>
#include <hip/hip_fp16.h>
#include <stdint.h>

#define S_LEN 1024
#define BATCH 64
#define HID   512
#define VOC   256

typedef _Float16 h2v __attribute__((ext_vector_type(2)));
typedef _Float16 h8v __attribute__((ext_vector_type(8)));
typedef float    f4v __attribute__((ext_vector_type(4)));

__device__ __forceinline__ float fdot2f(uint32_t w, uint32_t h, float c) {
#if __has_builtin(__builtin_amdgcn_fdot2)
  return __builtin_amdgcn_fdot2(__builtin_bit_cast(h2v, w),
                                __builtin_bit_cast(h2v, h), c, false);
#else
  h2v a = __builtin_bit_cast(h2v, w);
  h2v b = __builtin_bit_cast(h2v, h);
  return c + (float)a.x * (float)b.x + (float)a.y * (float)b.y;
#endif
}

// ---------------- prep kernels ----------------
// Wp[k2*HID + n] = fp16 pair (W_hh[2*k2][n], W_hh[2*k2+1][n])
__global__ void prep_whh(const float* __restrict__ whh, uint32_t* __restrict__ wp) {
  int idx = blockIdx.x * blockDim.x + threadIdx.x;   // 131072
  int k2 = idx >> 9;
  int n  = idx & 511;
  float a = whh[(2 * k2) * HID + n];
  float b = whh[(2 * k2 + 1) * HID + n];
  h2v p;
  p.x = (_Float16)a;
  p.y = (_Float16)b;
  wp[idx] = __builtin_bit_cast(uint32_t, p);
}

// W_hyT[v*HID + k] = fp16 W_hy[k][v]
__global__ void prep_why(const float* __restrict__ why, _Float16* __restrict__ wt) {
  int idx = blockIdx.x * blockDim.x + threadIdx.x;   // 131072
  int v = idx >> 9;
  int k = idx & 511;
  wt[idx] = (_Float16)why[k * VOC + v];
}

// expand acc0..3 with one h-pair against a 4-col weight word
#define DOT4(W, H)                                         \
  a0 = fdot2f((W).x, (H), a0); a1 = fdot2f((W).y, (H), a1); \
  a2 = fdot2f((W).z, (H), a2); a3 = fdot2f((W).w, (H), a3);

// ---------------- phase 1: recurrence ----------------
// 64 blocks (one per batch/chain), 512 threads = 8 waves, 1 block/CU.
// thread (kq=tid>>7 in [0,4), nb=tid&127): cols n0=nb*4..+3,
// k2-slices s in [kq*64, kq*64+64).
// Residency: s=0..39  VGPR via asm-volatile loads (160 regs; un-sinkable),
//            s=40..55 LDS (128 KB dynamic),
//            s=56..63 streamed from L1/L2 (64 KB/step).
__global__ __launch_bounds__(512, 2) void rnn_phase1(
    const int* __restrict__ x, const float* __restrict__ wih,
    const uint32_t* __restrict__ wp, const float* __restrict__ bh,
    __half* __restrict__ hbuf) {
  __shared__ __align__(16) uint32_t h2s[HID / 2];  // h as fp16 pairs (1 KB)
  __shared__ float part[4][HID];                   // 8 KB partials
  __shared__ int xtok[S_LEN];                      // 4 KB tokens
  extern __shared__ __align__(16) uint4 lw[];      // 16*512 uint4 = 128 KB

  const int b   = blockIdx.x;
  const int tid = threadIdx.x;
  const int kq  = tid >> 7;
  const int nb  = tid & 127;
  const int n0  = nb * 4;
  const int k2b = kq * 64;

  // ---- VGPR-resident slices: volatile asm loads cannot be sunk or remat'd
  uint4 w[40];
#pragma unroll
  for (int s = 0; s < 40; ++s) {
    const uint32_t* p = wp + (size_t)(k2b + s) * HID + n0;
    asm volatile("global_load_dwordx4 %0, %1, off" : "=v"(w[s]) : "v"(p));
  }
  asm volatile("s_waitcnt vmcnt(0)" ::: "memory");

  // ---- LDS-resident slices (own weights at lw[si*512+tid], b128 reads)
#pragma unroll
  for (int si = 0; si < 16; ++si)
    lw[si * 512 + tid] = *((const uint4*)&wp[(size_t)(k2b + 40 + si) * HID + n0]);

  xtok[tid]       = x[b * S_LEN + tid];
  xtok[tid + 512] = x[b * S_LEN + tid + 512];
  if (tid < HID / 2) h2s[tid] = 0u;  // h0 = 0
  const float bh_r = bh[tid];
  __syncthreads();

  for (int t = 0; t < S_LEN; ++t) {
    const int tok = xtok[t];
    const float xe = wih[tok * HID + tid];  // early issue; used in reduce

    // streamed slices issued early (loop-invariant addresses, L1-hot)
    uint4 g[8];
#pragma unroll
    for (int i = 0; i < 8; ++i)
      g[i] = *((const uint4*)&wp[(size_t)(k2b + 56 + i) * HID + n0]);

    float a0 = 0.f, a1 = 0.f, a2 = 0.f, a3 = 0.f;
    const uint4* hq = (const uint4*)&h2s[k2b];  // wave-uniform broadcast reads

    // VGPR slices s = 0..39
#pragma unroll
    for (int q = 0; q < 10; ++q) {
      const uint4 hc = hq[q];
      DOT4(w[q * 4 + 0], hc.x)
      DOT4(w[q * 4 + 1], hc.y)
      DOT4(w[q * 4 + 2], hc.z)
      DOT4(w[q * 4 + 3], hc.w)
    }
    // LDS slices s = 40..55
#pragma unroll
    for (int q = 0; q < 4; ++q) {
      const uint4 hc = hq[10 + q];
      const uint4 l0 = lw[(q * 4 + 0) * 512 + tid];
      const uint4 l1 = lw[(q * 4 + 1) * 512 + tid];
      const uint4 l2 = lw[(q * 4 + 2) * 512 + tid];
      const uint4 l3 = lw[(q * 4 + 3) * 512 + tid];
      DOT4(l0, hc.x)
      DOT4(l1, hc.y)
      DOT4(l2, hc.z)
      DOT4(l3, hc.w)
    }
    // streamed slices s = 56..63
#pragma unroll
    for (int q = 0; q < 2; ++q) {
      const uint4 hc = hq[14 + q];
      DOT4(g[q * 4 + 0], hc.x)
      DOT4(g[q * 4 + 1], hc.y)
      DOT4(g[q * 4 + 2], hc.z)
      DOT4(g[q * 4 + 3], hc.w)
    }

    *((float4*)&part[kq][n0]) = make_float4(a0, a1, a2, a3);
    __syncthreads();  // B1: partials ready; all h2s reads of step t done

    {
      float s = part[0][tid] + part[1][tid] + part[2][tid] + part[3][tid];
      s += xe + bh_r;
      const float e = __builtin_amdgcn_exp2f(s * 2.885390081777927f);  // e^(2s)
      const float h = 1.0f - 2.0f * __builtin_amdgcn_rcpf(e + 1.0f);
      const __half hh = __float2half(h);
      hbuf[(size_t)(t * BATCH + b) * HID + tid] = hh;  // history for phase 2
      ((__half*)h2s)[tid] = hh;                         // recurrent state
    }
    __syncthreads();  // B2: new h visible before next step's reads
  }
}

// ---------------- phase 2: y = h @ W_hy + b_y (fp16 MFMA, in-place over d_out) ----
__global__ __launch_bounds__(256, 1) void rnn_phase2(
    void* __restrict__ out_, const _Float16* __restrict__ wt,
    const float* __restrict__ by) {
  const int tid = threadIdx.x;
  const int w = tid >> 6;
  const int l = tid & 63;
  const int la = l & 15;
  const int lb = l >> 4;
  const int rowbase = blockIdx.x * 64 + w * 16;

  const _Float16* hb = (const _Float16*)out_;
  float* out = (float*)out_;

  h8v a[16];
  const _Float16* arow = hb + (size_t)(rowbase + la) * HID + lb * 8;
#pragma unroll
  for (int kk = 0; kk < 16; ++kk)
    a[kk] = *((const h8v*)(arow + kk * 32));

#pragma unroll 1
  for (int cb = 0; cb < 16; ++cb) {
    f4v acc = {0.f, 0.f, 0.f, 0.f};
    const _Float16* brow = wt + (size_t)(cb * 16 + la) * HID + lb * 8;
#pragma unroll
    for (int kk = 0; kk < 16; ++kk) {
      const h8v bf = *((const h8v*)(brow + kk * 32));
      acc = __builtin_amdgcn_mfma_f32_16x16x32_f16(a[kk], bf, acc, 0, 0, 0);
    }
    const int col = cb * 16 + la;
    const float byv = by[col];
#pragma unroll
    for (int r = 0; r < 4; ++r) {
      const int row = rowbase + lb * 4 + r;  // C/D: col = lane&15, row = (lane>>4)*4 + r
      out[(size_t)row * VOC + col] = acc[r] + byv;
    }
  }
}

// ---------------- launch ----------------
extern "C" void kernel_launch(void* const* d_in, const int* in_sizes, int n_in,
                              void* d_out, int out_size, void* d_ws, size_t ws_size,
                              hipStream_t stream) {
  const int*   x   = (const int*)d_in[0];
  const float* wih = (const float*)d_in[1];
  const float* whh = (const float*)d_in[2];
  const float* bh  = (const float*)d_in[3];
  const float* why = (const float*)d_in[4];
  const float* by  = (const float*)d_in[5];

  uint32_t* wp = (uint32_t*)d_ws;                          // 512 KB packed fp16 W_hh
  _Float16* wt = (_Float16*)((char*)d_ws + 512 * 1024);    // 256 KB fp16 W_hy^T

  hipLaunchKernelGGL(prep_whh, dim3(512), dim3(256), 0, stream, whh, wp);
  hipLaunchKernelGGL(prep_why, dim3(512), dim3(256), 0, stream, why, wt);
  hipLaunchKernelGGL(rnn_phase1, dim3(BATCH), dim3(512), 131072, stream,
                     x, wih, wp, bh, (__half*)d_out);
  hipLaunchKernelGGL(rnn_phase2, dim3((S_LEN * BATCH) / 64), dim3(256), 0, stream,
                     d_out, wt, by);
}